// Round 9
// baseline (1190.465 us; speedup 1.0000x reference)
//
#include <hip/hip_runtime.h>
#include <hip/hip_bf16.h>
#include <math.h>

// GCN push scheme: bucket sort edges by dst>>9 (512 nodes/bucket) ->
// per-(bucket,slice) block scatters bf16 src features into XOR-swizzled
// LDS fp32 accumulators (no per-node CSR, no wave reduce, no epilogue
// serialization) -> coalesced global-atomic merge -> thread-per-node dense
// kernels with uniform scalar-cache weight reads.

#define CW    512
#define CSH   9
#define MAXBUKC 256   // n <= 131072 (17-bit src packing)

static inline int cdiv(int a, int b) { return (a + b - 1) / b; }

__device__ inline unsigned int bf16_rn(float f) {
    unsigned int u = __float_as_uint(f);
    return (u + 0x7fffu + ((u >> 16) & 1u)) >> 16;
}
#define BLO(u) __uint_as_float((u) << 16)
#define BHI(u) __uint_as_float((u) & 0xffff0000u)

// ---------------- bucket build (r6-proven) ----------------

__global__ void __launch_bounds__(256) k_bhist(const int* __restrict__ dst,
                                               int* __restrict__ bcnt, int e, int nbuk) {
    __shared__ int lh[MAXBUKC];
    for (int b = threadIdx.x; b < nbuk; b += 256) lh[b] = 0;
    __syncthreads();
    int base = blockIdx.x * 4096;
#pragma unroll
    for (int j = 0; j < 16; j++) {
        int i = base + j * 256 + threadIdx.x;
        if (i < e) atomicAdd(&lh[__builtin_nontemporal_load(dst + i) >> CSH], 1);
    }
    __syncthreads();
    for (int b = threadIdx.x; b < nbuk; b += 256) {
        int c = lh[b];
        if (c) atomicAdd(&bcnt[b], c);
    }
}

__global__ void __launch_bounds__(256) k_bscan(const int* __restrict__ bcnt,
                                               int* __restrict__ boff, int* __restrict__ gcur,
                                               int nbuk, int e) {
    __shared__ int sh[256];
    int t = threadIdx.x;
    int v = (t < nbuk) ? bcnt[t] : 0;
    sh[t] = v;
    __syncthreads();
    for (int o = 1; o < 256; o <<= 1) {
        int u = (t >= o) ? sh[t - o] : 0;
        __syncthreads();
        sh[t] += u;
        __syncthreads();
    }
    if (t < nbuk) { int ex = sh[t] - v; boff[t] = ex; gcur[t] = ex; }
    if (t == 0) boff[nbuk] = e;
}

__global__ void __launch_bounds__(256) k_bscatter(const int* __restrict__ src,
                                                  const int* __restrict__ dst,
                                                  int* __restrict__ gcur,
                                                  int* __restrict__ ebuf, int e, int nbuk) {
    __shared__ int lh[MAXBUKC];
    __shared__ int lb[MAXBUKC];
    int db[32];
    for (int b = threadIdx.x; b < nbuk; b += 256) lh[b] = 0;
    __syncthreads();
    int base = blockIdx.x * 8192;
#pragma unroll
    for (int j = 0; j < 32; j++) {
        int i = base + j * 256 + threadIdx.x;
        db[j] = (i < e) ? __builtin_nontemporal_load(dst + i) : 0;
        if (i < e) atomicAdd(&lh[db[j] >> CSH], 1);
    }
    __syncthreads();
    for (int b = threadIdx.x; b < nbuk; b += 256) {
        int c = lh[b];
        lb[b] = c ? atomicAdd(&gcur[b], c) : 0;
        lh[b] = 0;
    }
    __syncthreads();
#pragma unroll
    for (int j = 0; j < 32; j++) {
        int i = base + j * 256 + threadIdx.x;
        if (i < e) {
            int d = db[j];
            int s = __builtin_nontemporal_load(src + i);
            int b = d >> CSH;
            int r = atomicAdd(&lh[b], 1);
            ebuf[lb[b] + r] = ((d & (CW - 1)) << 17) | s;
        }
    }
}

// ---------------- degree -> dinv ----------------

__global__ void __launch_bounds__(CW) k_deg(const int* __restrict__ ebuf,
                                            const int* __restrict__ boff,
                                            float* __restrict__ dinv, int n) {
    __shared__ int cnt[CW];
    int t = threadIdx.x;
    cnt[t] = 0;
    __syncthreads();
    int beg = boff[blockIdx.x], end = boff[blockIdx.x + 1];
    for (int k = beg + t; k < end; k += CW)
        atomicAdd(&cnt[__builtin_nontemporal_load(ebuf + k) >> 17], 1);
    __syncthreads();
    int node = blockIdx.x * CW + t;
    if (node < n) dinv[node] = rsqrtf((float)cnt[t] + 1.0f);
}

// ---------------- pre-scale + bf16 pack ----------------

__global__ void __launch_bounds__(256) k_xscale(const float* __restrict__ x,
                                                const float* __restrict__ dinv,
                                                unsigned int* __restrict__ xs, int n4) {
    int i = blockIdx.x * blockDim.x + threadIdx.x;
    if (i >= n4) return;
    float dd = dinv[i >> 2];
    float4 v = ((const float4*)x)[i];
    uint2 o;
    o.x = bf16_rn(v.x * dd) | (bf16_rn(v.y * dd) << 16);
    o.y = bf16_rn(v.z * dd) | (bf16_rn(v.w * dd) << 16);
    ((uint2*)xs)[i] = o;
}

// ---------------- push aggregation: 16-feat (xs) ----------------

__device__ inline void add8(float* p, int m, int j0, uint4 v) {
    atomicAdd(p + ((j0 + 0) ^ m), BLO(v.x)); atomicAdd(p + ((j0 + 1) ^ m), BHI(v.x));
    atomicAdd(p + ((j0 + 2) ^ m), BLO(v.y)); atomicAdd(p + ((j0 + 3) ^ m), BHI(v.y));
    atomicAdd(p + ((j0 + 4) ^ m), BLO(v.z)); atomicAdd(p + ((j0 + 5) ^ m), BHI(v.z));
    atomicAdd(p + ((j0 + 6) ^ m), BLO(v.w)); atomicAdd(p + ((j0 + 7) ^ m), BHI(v.w));
}

__global__ void __launch_bounds__(256) k_push16(const int* __restrict__ ebuf,
                                                const int* __restrict__ boff,
                                                const unsigned int* __restrict__ xs,
                                                float* __restrict__ agg, int n) {
    __shared__ float acc[CW * 16];   // 32 KB, XOR-swizzled banks
    for (int i = threadIdx.x; i < CW * 16; i += 256) acc[i] = 0.f;
    __syncthreads();
    int bucket = blockIdx.x >> 2, slice = blockIdx.x & 3;
    int b0 = boff[bucket], len = boff[bucket + 1] - b0;
    int sb = b0 + ((len * slice) >> 2);
    int se = b0 + ((len * (slice + 1)) >> 2);
    const uint4* x4 = (const uint4*)xs;
    int k = sb + (int)threadIdx.x * 2;
    for (; k + 1 < se; k += 512) {
        int p0 = __builtin_nontemporal_load(ebuf + k);
        int p1 = __builtin_nontemporal_load(ebuf + k + 1);
        int s0 = p0 & 0x1FFFF, d0 = p0 >> 17;
        int s1 = p1 & 0x1FFFF, d1 = p1 >> 17;
        uint4 a0 = x4[(size_t)s0 * 2], a1 = x4[(size_t)s0 * 2 + 1];
        uint4 c0 = x4[(size_t)s1 * 2], c1 = x4[(size_t)s1 * 2 + 1];
        { float* p = acc + d0 * 16; int m = d0 & 15; add8(p, m, 0, a0); add8(p, m, 8, a1); }
        { float* p = acc + d1 * 16; int m = d1 & 15; add8(p, m, 0, c0); add8(p, m, 8, c1); }
    }
    if (k < se) {
        int p0 = __builtin_nontemporal_load(ebuf + k);
        int s0 = p0 & 0x1FFFF, d0 = p0 >> 17;
        uint4 a0 = x4[(size_t)s0 * 2], a1 = x4[(size_t)s0 * 2 + 1];
        float* p = acc + d0 * 16; int m = d0 & 15; add8(p, m, 0, a0); add8(p, m, 8, a1);
    }
    __syncthreads();
    int nbase = bucket * CW;
    for (int i = threadIdx.x; i < CW * 16; i += 256) {
        int nl = i >> 4, f = i & 15;
        int node = nbase + nl;
        float v = acc[nl * 16 + (f ^ (nl & 15))];
        if (node < n && v != 0.f) atomicAdd(&agg[(size_t)node * 16 + f], v);
    }
}

// ---------------- push aggregation: 32-feat (h1s) ----------------

__global__ void __launch_bounds__(512) k_push32(const int* __restrict__ ebuf,
                                                const int* __restrict__ boff,
                                                const unsigned int* __restrict__ h1s,
                                                float* __restrict__ agg, int n) {
    __shared__ float acc[CW * 32];   // 64 KB, XOR-swizzled banks
    for (int i = threadIdx.x; i < CW * 32; i += 512) acc[i] = 0.f;
    __syncthreads();
    int bucket = blockIdx.x >> 2, slice = blockIdx.x & 3;
    int b0 = boff[bucket], len = boff[bucket + 1] - b0;
    int sb = b0 + ((len * slice) >> 2);
    int se = b0 + ((len * (slice + 1)) >> 2);
    const uint4* h4 = (const uint4*)h1s;
    int k = sb + (int)threadIdx.x * 2;
    for (; k + 1 < se; k += 1024) {
        int p0 = __builtin_nontemporal_load(ebuf + k);
        int p1 = __builtin_nontemporal_load(ebuf + k + 1);
        int s0 = p0 & 0x1FFFF, d0 = p0 >> 17;
        int s1 = p1 & 0x1FFFF, d1 = p1 >> 17;
        uint4 a0 = h4[(size_t)s0 * 4 + 0], a1 = h4[(size_t)s0 * 4 + 1];
        uint4 a2 = h4[(size_t)s0 * 4 + 2], a3 = h4[(size_t)s0 * 4 + 3];
        uint4 c0 = h4[(size_t)s1 * 4 + 0], c1 = h4[(size_t)s1 * 4 + 1];
        uint4 c2 = h4[(size_t)s1 * 4 + 2], c3 = h4[(size_t)s1 * 4 + 3];
        { float* p = acc + d0 * 32; int m = d0 & 31;
          add8(p, m, 0, a0); add8(p, m, 8, a1); add8(p, m, 16, a2); add8(p, m, 24, a3); }
        { float* p = acc + d1 * 32; int m = d1 & 31;
          add8(p, m, 0, c0); add8(p, m, 8, c1); add8(p, m, 16, c2); add8(p, m, 24, c3); }
    }
    if (k < se) {
        int p0 = __builtin_nontemporal_load(ebuf + k);
        int s0 = p0 & 0x1FFFF, d0 = p0 >> 17;
        uint4 a0 = h4[(size_t)s0 * 4 + 0], a1 = h4[(size_t)s0 * 4 + 1];
        uint4 a2 = h4[(size_t)s0 * 4 + 2], a3 = h4[(size_t)s0 * 4 + 3];
        float* p = acc + d0 * 32; int m = d0 & 31;
        add8(p, m, 0, a0); add8(p, m, 8, a1); add8(p, m, 16, a2); add8(p, m, 24, a3);
    }
    __syncthreads();
    int nbase = bucket * CW;
    for (int i = threadIdx.x; i < CW * 32; i += 512) {
        int nl = i >> 5, f = i & 31;
        int node = nbase + nl;
        float v = acc[nl * 32 + (f ^ (nl & 31))];
        if (node < n && v != 0.f) atomicAdd(&agg[(size_t)node * 32 + f], v);
    }
}

// ---------------- push aggregation: scalar (t2) ----------------

__global__ void __launch_bounds__(256) k_push1(const int* __restrict__ ebuf,
                                               const int* __restrict__ boff,
                                               const float* __restrict__ t2,
                                               float* __restrict__ aggo, int n) {
    __shared__ float acc[CW];
    for (int i = threadIdx.x; i < CW; i += 256) acc[i] = 0.f;
    __syncthreads();
    int bucket = blockIdx.x >> 2, slice = blockIdx.x & 3;
    int b0 = boff[bucket], len = boff[bucket + 1] - b0;
    int sb = b0 + ((len * slice) >> 2);
    int se = b0 + ((len * (slice + 1)) >> 2);
    for (int k = sb + threadIdx.x; k < se; k += 256) {
        int pv = __builtin_nontemporal_load(ebuf + k);
        atomicAdd(&acc[pv >> 17], t2[pv & 0x1FFFF]);
    }
    __syncthreads();
    int nbase = bucket * CW;
    for (int i = threadIdx.x; i < CW; i += 256) {
        int node = nbase + i;
        float v = acc[i];
        if (node < n && v != 0.f) atomicAdd(&aggo[node], v);
    }
}

// ---------------- dense layers (thread per node, scalar-cache weights) ----------------

__global__ void __launch_bounds__(256) k_dense1(const float* __restrict__ agg,
                                                const unsigned int* __restrict__ xs,
                                                const float* __restrict__ dinv,
                                                const float* __restrict__ W1,
                                                const float* __restrict__ b1,
                                                unsigned int* __restrict__ h1s, int n) {
    int node = blockIdx.x * 256 + threadIdx.x;
    if (node >= n) return;
    float dd = dinv[node];
    const uint4* x4 = (const uint4*)xs;
    uint4 s0 = x4[(size_t)node * 2], s1 = x4[(size_t)node * 2 + 1];
    const float4* a4 = (const float4*)(agg + (size_t)node * 16);
    float4 q0 = a4[0], q1 = a4[1], q2 = a4[2], q3 = a4[3];
    float in[16];
    in[0]  = (q0.x + BLO(s0.x)) * dd; in[1]  = (q0.y + BHI(s0.x)) * dd;
    in[2]  = (q0.z + BLO(s0.y)) * dd; in[3]  = (q0.w + BHI(s0.y)) * dd;
    in[4]  = (q1.x + BLO(s0.z)) * dd; in[5]  = (q1.y + BHI(s0.z)) * dd;
    in[6]  = (q1.z + BLO(s0.w)) * dd; in[7]  = (q1.w + BHI(s0.w)) * dd;
    in[8]  = (q2.x + BLO(s1.x)) * dd; in[9]  = (q2.y + BHI(s1.x)) * dd;
    in[10] = (q2.z + BLO(s1.y)) * dd; in[11] = (q2.w + BHI(s1.y)) * dd;
    in[12] = (q3.x + BLO(s1.z)) * dd; in[13] = (q3.y + BHI(s1.z)) * dd;
    in[14] = (q3.z + BLO(s1.w)) * dd; in[15] = (q3.w + BHI(s1.w)) * dd;
    unsigned int hw[16];
#pragma unroll
    for (int c = 0; c < 16; c++) {
        float o0 = b1[2 * c], o1 = b1[2 * c + 1];
#pragma unroll
        for (int k = 0; k < 16; k++) {
            o0 += in[k] * W1[k * 32 + 2 * c];
            o1 += in[k] * W1[k * 32 + 2 * c + 1];
        }
        o0 = fmaxf(o0, 0.f) * dd;
        o1 = fmaxf(o1, 0.f) * dd;
        hw[c] = bf16_rn(o0) | (bf16_rn(o1) << 16);
    }
    uint4* o4 = (uint4*)(h1s + (size_t)node * 16);
    o4[0] = make_uint4(hw[0], hw[1], hw[2], hw[3]);
    o4[1] = make_uint4(hw[4], hw[5], hw[6], hw[7]);
    o4[2] = make_uint4(hw[8], hw[9], hw[10], hw[11]);
    o4[3] = make_uint4(hw[12], hw[13], hw[14], hw[15]);
}

__global__ void __launch_bounds__(256) k_dense2(const float* __restrict__ agg,
                                                const unsigned int* __restrict__ h1s,
                                                const float* __restrict__ dinv,
                                                const float* __restrict__ W2,
                                                const float* __restrict__ b2,
                                                const float* __restrict__ W3,
                                                float* __restrict__ t2, int n) {
    int node = blockIdx.x * 256 + threadIdx.x;
    if (node >= n) return;
    float dd = dinv[node];
    const uint4* h4 = (const uint4*)h1s;
    float in[32];
    const float4* a4 = (const float4*)(agg + (size_t)node * 32);
#pragma unroll
    for (int q = 0; q < 4; q++) {
        uint4 sv = h4[(size_t)node * 4 + q];
        float4 v0 = a4[2 * q], v1 = a4[2 * q + 1];
        in[8 * q + 0] = (v0.x + BLO(sv.x)) * dd; in[8 * q + 1] = (v0.y + BHI(sv.x)) * dd;
        in[8 * q + 2] = (v0.z + BLO(sv.y)) * dd; in[8 * q + 3] = (v0.w + BHI(sv.y)) * dd;
        in[8 * q + 4] = (v1.x + BLO(sv.z)) * dd; in[8 * q + 5] = (v1.y + BHI(sv.z)) * dd;
        in[8 * q + 6] = (v1.z + BLO(sv.w)) * dd; in[8 * q + 7] = (v1.w + BHI(sv.w)) * dd;
    }
    float o[64];
#pragma unroll
    for (int c = 0; c < 64; c++) o[c] = b2[c];
#pragma unroll
    for (int k = 0; k < 32; k++) {
        float ik = in[k];
#pragma unroll
        for (int c = 0; c < 64; c++) o[c] += ik * W2[k * 64 + c];
    }
    float p = 0.f;
#pragma unroll
    for (int c = 0; c < 64; c++) p += fmaxf(o[c], 0.f) * W3[c];
    t2[node] = p * dd;
}

// ---------------- final sigmoid ----------------

__global__ void __launch_bounds__(256) k_sig(const float* __restrict__ aggo,
                                             const float* __restrict__ t2,
                                             const float* __restrict__ dinv,
                                             const float* __restrict__ b3,
                                             float* __restrict__ out, int n) {
    int i = blockIdx.x * 256 + threadIdx.x;
    if (i < n) {
        float v = (aggo[i] + t2[i]) * dinv[i] + b3[0];
        out[i] = 1.0f / (1.0f + expf(-v));
    }
}

// ---------------- launch ----------------

extern "C" void kernel_launch(void* const* d_in, const int* in_sizes, int n_in,
                              void* d_out, int out_size, void* d_ws, size_t ws_size,
                              hipStream_t stream) {
    const float* x  = (const float*)d_in[0];
    const int*   ei = (const int*)d_in[1];
    const float* W1 = (const float*)d_in[2];
    const float* b1 = (const float*)d_in[3];
    const float* W2 = (const float*)d_in[4];
    const float* b2 = (const float*)d_in[5];
    const float* W3 = (const float*)d_in[6];
    const float* b3 = (const float*)d_in[7];

    const int n = in_sizes[0] / 16;
    const int e = in_sizes[1] / 2;
    const int* src = ei;
    const int* dst = ei + e;
    const int nbuk = cdiv(n, CW);   // 196 for n=100000

    auto rup = [](size_t v) { return (v + 15) & ~(size_t)15; };
    char* wp = (char*)d_ws;
    auto alloc = [&](size_t elems) { void* p = wp; wp += rup(elems) * 4; return p; };
    int*   bcnt  = (int*)  alloc(MAXBUKC);
    int*   boff  = (int*)  alloc(MAXBUKC + 1);
    int*   gcur  = (int*)  alloc(MAXBUKC);
    float* dinv  = (float*)alloc(n);
    int*   ebuf  = (int*)  alloc(e);
    unsigned int* xs  = (unsigned int*)alloc((size_t)8 * n);   // 16 bf16 / node
    unsigned int* h1s = (unsigned int*)alloc((size_t)16 * n);  // 32 bf16 / node
    float* agg16 = (float*)alloc((size_t)16 * n);
    float* agg32 = (float*)alloc((size_t)32 * n);
    float* aggo  = (float*)alloc(n);
    char*  zend  = wp;            // agg16..aggo zero region
    float* t2    = (float*)alloc(n);

    float* out = (float*)d_out;
    const int B = 256;
    const int pushGrid = nbuk * 4;

    hipMemsetAsync(bcnt, 0, MAXBUKC * 4, stream);
    hipMemsetAsync(agg16, 0, (size_t)(zend - (char*)agg16), stream);

    k_bhist<<<cdiv(e, 4096), B, 0, stream>>>(dst, bcnt, e, nbuk);
    k_bscan<<<1, 256, 0, stream>>>(bcnt, boff, gcur, nbuk, e);
    k_bscatter<<<cdiv(e, 8192), B, 0, stream>>>(src, dst, gcur, ebuf, e, nbuk);
    k_deg<<<nbuk, CW, 0, stream>>>(ebuf, boff, dinv, n);
    k_xscale<<<cdiv(n * 4, B), B, 0, stream>>>(x, dinv, xs, n * 4);

    // Layer 1
    k_push16<<<pushGrid, 256, 0, stream>>>(ebuf, boff, xs, agg16, n);
    k_dense1<<<cdiv(n, B), B, 0, stream>>>(agg16, xs, dinv, W1, b1, h1s, n);

    // Layer 2
    k_push32<<<pushGrid, 512, 0, stream>>>(ebuf, boff, h1s, agg32, n);
    k_dense2<<<cdiv(n, B), B, 0, stream>>>(agg32, h1s, dinv, W2, b2, W3, t2, n);

    // Layer 3
    k_push1<<<pushGrid, 256, 0, stream>>>(ebuf, boff, t2, aggo, n);
    k_sig<<<cdiv(n, B), B, 0, stream>>>(aggo, t2, dinv, b3, out, n);
}

// Round 10
// 264.111 us; speedup vs baseline: 4.5074x; 4.5074x over previous
//
#include <hip/hip_runtime.h>
#include <hip/hip_bf16.h>
#include <math.h>

// GCN: LDS-staged bucket sort (512 nodes/bucket, coalesced chunk writes) ->
// per-bucket exact CSR (+dinv) -> wave-per-node PULL aggregation on bf16
// features (2-deep unrolled gathers, fp32 accum, self-term+norm fused) ->
// separate thread-per-node dense kernels (scalar-cache weights).

#define CW    512
#define CSH   9
#define MAXBUKC 256   // n <= 131072 (17-bit src packing)
#define EPB   8192    // edges per bscatter block

static inline int cdiv(int a, int b) { return (a + b - 1) / b; }

__device__ inline unsigned int bf16_rn(float f) {
    unsigned int u = __float_as_uint(f);
    return (u + 0x7fffu + ((u >> 16) & 1u)) >> 16;
}
#define BLO(u) __uint_as_float((u) << 16)
#define BHI(u) __uint_as_float((u) & 0xffff0000u)

#define UNPACK_ADD(A, V) \
    A[0] += BLO(V.x); A[1] += BHI(V.x); \
    A[2] += BLO(V.y); A[3] += BHI(V.y); \
    A[4] += BLO(V.z); A[5] += BHI(V.z); \
    A[6] += BLO(V.w); A[7] += BHI(V.w);

// ---------------- bucket build ----------------

__global__ void __launch_bounds__(256) k_bhist(const int* __restrict__ dst,
                                               int* __restrict__ bcnt, int e, int nbuk) {
    __shared__ int lh[MAXBUKC];
    for (int b = threadIdx.x; b < nbuk; b += 256) lh[b] = 0;
    __syncthreads();
    int base = blockIdx.x * 4096;
#pragma unroll
    for (int j = 0; j < 16; j++) {
        int i = base + j * 256 + threadIdx.x;
        if (i < e) atomicAdd(&lh[dst[i] >> CSH], 1);
    }
    __syncthreads();
    for (int b = threadIdx.x; b < nbuk; b += 256) {
        int c = lh[b];
        if (c) atomicAdd(&bcnt[b], c);
    }
}

__global__ void __launch_bounds__(256) k_bscan(const int* __restrict__ bcnt,
                                               int* __restrict__ boff, int* __restrict__ gcur,
                                               int nbuk, int e) {
    __shared__ int sh[256];
    int t = threadIdx.x;
    int v = (t < nbuk) ? bcnt[t] : 0;
    sh[t] = v;
    __syncthreads();
    for (int o = 1; o < 256; o <<= 1) {
        int u = (t >= o) ? sh[t - o] : 0;
        __syncthreads();
        sh[t] += u;
        __syncthreads();
    }
    if (t < nbuk) { int ex = sh[t] - v; boff[t] = ex; gcur[t] = ex; }
    if (t == 0) boff[nbuk] = e;
}

// LDS-staged scatter: sort this block's edges into bucket order in LDS,
// then write each bucket's chunk densely (near-coalesced, no 4B scatters).
__global__ void __launch_bounds__(256) k_bscatter(const int* __restrict__ src,
                                                  const int* __restrict__ dst,
                                                  int* __restrict__ gcur,
                                                  int* __restrict__ ebuf, int e, int nbuk) {
    __shared__ int lh[MAXBUKC];            // counts -> cursors
    __shared__ int lo[MAXBUKC];            // local exclusive offsets
    __shared__ int lb[MAXBUKC];            // global bases
    __shared__ int sh[256];
    __shared__ int stage[EPB];             // 32 KB
    __shared__ unsigned char bkOf[EPB];    // 8 KB
    int db[32];
    int t = threadIdx.x;
    for (int b = t; b < nbuk; b += 256) lh[b] = 0;
    __syncthreads();
    int base = blockIdx.x * EPB;
#pragma unroll
    for (int j = 0; j < 32; j++) {
        int i = base + j * 256 + t;
        db[j] = (i < e) ? dst[i] : -1;
        if (i < e) atomicAdd(&lh[db[j] >> CSH], 1);
    }
    __syncthreads();
    int c = (t < nbuk) ? lh[t] : 0;
    int gb = (t < nbuk && c) ? atomicAdd(&gcur[t], c) : 0;
    sh[t] = c;
    __syncthreads();
    for (int o = 1; o < 256; o <<= 1) {
        int u = (t >= o) ? sh[t - o] : 0;
        __syncthreads();
        sh[t] += u;
        __syncthreads();
    }
    if (t < nbuk) { lo[t] = sh[t] - c; lb[t] = gb; lh[t] = 0; }
    __syncthreads();
#pragma unroll
    for (int j = 0; j < 32; j++) {
        int i = base + j * 256 + t;
        if (i < e) {
            int d = db[j];
            int b = d >> CSH;
            int s = src[i];
            int r = atomicAdd(&lh[b], 1);
            int slot = lo[b] + r;
            stage[slot] = ((d & (CW - 1)) << 17) | s;
            bkOf[slot] = (unsigned char)b;
        }
    }
    __syncthreads();
    int tot = min(EPB, e - base);
#pragma unroll
    for (int j = 0; j < 32; j++) {
        int slot = j * 256 + t;
        if (slot < tot) {
            int b = bkOf[slot];
            ebuf[lb[b] + (slot - lo[b])] = stage[slot];
        }
    }
}

// ---------------- per-bucket exact CSR + dinv ----------------

__global__ void __launch_bounds__(CW) k_csr2(const int* __restrict__ ebuf,
                                             const int* __restrict__ boff,
                                             int* __restrict__ rowstart,
                                             int* __restrict__ csr_src,
                                             float* __restrict__ dinv, int n, int e) {
    __shared__ int cnt[CW];
    __shared__ int offs[CW];
    int t = threadIdx.x;
    cnt[t] = 0;
    __syncthreads();
    int beg = boff[blockIdx.x], end = boff[blockIdx.x + 1];
    for (int k = beg + t; k < end; k += CW)
        atomicAdd(&cnt[ebuf[k] >> 17], 1);
    __syncthreads();
    int v = cnt[t];
    offs[t] = v;
    __syncthreads();
    for (int o = 1; o < CW; o <<= 1) {
        int u = (t >= o) ? offs[t - o] : 0;
        __syncthreads();
        offs[t] += u;
        __syncthreads();
    }
    int ex = offs[t] - v;
    int node = blockIdx.x * CW + t;
    if (node < n) {
        rowstart[node] = beg + ex;
        dinv[node] = rsqrtf((float)v + 1.0f);
    }
    cnt[t] = ex;
    __syncthreads();
    for (int k = beg + t; k < end; k += CW) {
        int pv = ebuf[k];
        int dl = pv >> 17, s = pv & 0x1FFFF;
        int r = atomicAdd(&cnt[dl], 1);
        csr_src[beg + r] = s;
    }
    if (blockIdx.x == 0 && t == 0) rowstart[n] = e;
}

// ---------------- pre-scale + bf16 pack ----------------

__global__ void __launch_bounds__(256) k_xscale(const float* __restrict__ x,
                                                const float* __restrict__ dinv,
                                                unsigned int* __restrict__ xs, int n4) {
    int i = blockIdx.x * blockDim.x + threadIdx.x;
    if (i >= n4) return;
    float dd = dinv[i >> 2];
    float4 v = ((const float4*)x)[i];
    uint2 o;
    o.x = bf16_rn(v.x * dd) | (bf16_rn(v.y * dd) << 16);
    o.y = bf16_rn(v.z * dd) | (bf16_rn(v.w * dd) << 16);
    ((uint2*)xs)[i] = o;
}

// ---------------- Layer-1 pull: agg16 = A_hat @ x (normalized, fp32 out) ----------------
// wave/node; 2 lanes/edge; 2-deep unroll -> 64 gathers outstanding.

__global__ void __launch_bounds__(256) k_pull16(const int* __restrict__ rowstart,
                                                const int* __restrict__ csr_src,
                                                const float* __restrict__ dinv,
                                                const unsigned int* __restrict__ xs,
                                                float* __restrict__ agg16, int n) {
    int wid = (blockIdx.x * blockDim.x + threadIdx.x) >> 6;
    if (wid >= n) return;
    int lane = threadIdx.x & 63;
    int half = lane & 1;
    int beg = rowstart[wid], end = rowstart[wid + 1];
    const uint4* x4 = (const uint4*)xs;   // 2 uint4 per node row
    float acc[8], ac1[8];
#pragma unroll
    for (int i = 0; i < 8; i++) { acc[i] = 0.f; ac1[i] = 0.f; }
    int k = beg + (lane >> 1);
    for (; k + 32 < end; k += 64) {
        int s0 = __builtin_nontemporal_load(csr_src + k);
        int s1 = __builtin_nontemporal_load(csr_src + k + 32);
        uint4 v0 = x4[(size_t)s0 * 2 + half];
        uint4 v1 = x4[(size_t)s1 * 2 + half];
        UNPACK_ADD(acc, v0);
        UNPACK_ADD(ac1, v1);
    }
    if (k < end) {
        int s0 = __builtin_nontemporal_load(csr_src + k);
        uint4 v0 = x4[(size_t)s0 * 2 + half];
        UNPACK_ADD(acc, v0);
    }
#pragma unroll
    for (int i = 0; i < 8; i++) acc[i] += ac1[i];
#pragma unroll
    for (int off = 2; off < 64; off <<= 1)
#pragma unroll
        for (int i = 0; i < 8; i++) acc[i] += __shfl_xor(acc[i], off);
    float dd = dinv[wid];
    uint4 sv = x4[(size_t)wid * 2 + half];
    UNPACK_ADD(acc, sv);
    if (lane < 2) {
        float4* o4 = (float4*)(agg16 + (size_t)wid * 16 + half * 8);
        o4[0] = make_float4(acc[0] * dd, acc[1] * dd, acc[2] * dd, acc[3] * dd);
        o4[1] = make_float4(acc[4] * dd, acc[5] * dd, acc[6] * dd, acc[7] * dd);
    }
}

// ---------------- dense1: h1s = bf16(relu(agg16@W1+b1) * dinv) ----------------

__global__ void __launch_bounds__(256) k_dense1(const float* __restrict__ agg,
                                                const float* __restrict__ dinv,
                                                const float* __restrict__ W1,
                                                const float* __restrict__ b1,
                                                unsigned int* __restrict__ h1s, int n) {
    int node = blockIdx.x * 256 + threadIdx.x;
    if (node >= n) return;
    float dd = dinv[node];
    float in[16];
    const float4* a4 = (const float4*)(agg + (size_t)node * 16);
#pragma unroll
    for (int f = 0; f < 4; f++) {
        float4 v = a4[f];
        in[4 * f] = v.x; in[4 * f + 1] = v.y; in[4 * f + 2] = v.z; in[4 * f + 3] = v.w;
    }
    unsigned int hw[16];
#pragma unroll
    for (int c = 0; c < 16; c++) {
        float o0 = b1[2 * c], o1 = b1[2 * c + 1];
#pragma unroll
        for (int k = 0; k < 16; k++) {
            o0 += in[k] * W1[k * 32 + 2 * c];
            o1 += in[k] * W1[k * 32 + 2 * c + 1];
        }
        hw[c] = bf16_rn(fmaxf(o0, 0.f) * dd) | (bf16_rn(fmaxf(o1, 0.f) * dd) << 16);
    }
    uint4* o4 = (uint4*)(h1s + (size_t)node * 16);
    o4[0] = make_uint4(hw[0], hw[1], hw[2], hw[3]);
    o4[1] = make_uint4(hw[4], hw[5], hw[6], hw[7]);
    o4[2] = make_uint4(hw[8], hw[9], hw[10], hw[11]);
    o4[3] = make_uint4(hw[12], hw[13], hw[14], hw[15]);
}

// ---------------- Layer-2 pull: agg32 = A_hat @ h1 (normalized, fp32 out) ----------------
// wave/node; 4 lanes/edge; 2-deep unroll -> 32 gathers outstanding.

__global__ void __launch_bounds__(256) k_pull32(const int* __restrict__ rowstart,
                                                const int* __restrict__ csr_src,
                                                const float* __restrict__ dinv,
                                                const unsigned int* __restrict__ h1s,
                                                float* __restrict__ agg32, int n) {
    int wid = (blockIdx.x * blockDim.x + threadIdx.x) >> 6;
    if (wid >= n) return;
    int lane = threadIdx.x & 63;
    int f4 = lane & 3;
    int beg = rowstart[wid], end = rowstart[wid + 1];
    const uint4* h4 = (const uint4*)h1s;  // 4 uint4 per node row
    float acc[8], ac1[8];
#pragma unroll
    for (int i = 0; i < 8; i++) { acc[i] = 0.f; ac1[i] = 0.f; }
    int k = beg + (lane >> 2);
    for (; k + 16 < end; k += 32) {
        int s0 = __builtin_nontemporal_load(csr_src + k);
        int s1 = __builtin_nontemporal_load(csr_src + k + 16);
        uint4 v0 = h4[(size_t)s0 * 4 + f4];
        uint4 v1 = h4[(size_t)s1 * 4 + f4];
        UNPACK_ADD(acc, v0);
        UNPACK_ADD(ac1, v1);
    }
    if (k < end) {
        int s0 = __builtin_nontemporal_load(csr_src + k);
        uint4 v0 = h4[(size_t)s0 * 4 + f4];
        UNPACK_ADD(acc, v0);
    }
#pragma unroll
    for (int i = 0; i < 8; i++) acc[i] += ac1[i];
#pragma unroll
    for (int off = 4; off < 64; off <<= 1)
#pragma unroll
        for (int i = 0; i < 8; i++) acc[i] += __shfl_xor(acc[i], off);
    float dd = dinv[wid];
    uint4 sv = h4[(size_t)wid * 4 + f4];
    UNPACK_ADD(acc, sv);
    if (lane < 4) {
        float4* o4 = (float4*)(agg32 + (size_t)wid * 32 + f4 * 8);
        o4[0] = make_float4(acc[0] * dd, acc[1] * dd, acc[2] * dd, acc[3] * dd);
        o4[1] = make_float4(acc[4] * dd, acc[5] * dd, acc[6] * dd, acc[7] * dd);
    }
}

// ---------------- dense2: t2 = (relu(agg32@W2+b2) @ W3) * dinv ----------------
// col-blocked (4 x 16) to keep VGPRs low; W reads are uniform scalar loads.

__global__ void __launch_bounds__(256) k_dense2(const float* __restrict__ agg,
                                                const float* __restrict__ dinv,
                                                const float* __restrict__ W2,
                                                const float* __restrict__ b2,
                                                const float* __restrict__ W3,
                                                float* __restrict__ t2, int n) {
    int node = blockIdx.x * 256 + threadIdx.x;
    if (node >= n) return;
    float in[32];
    const float4* a4 = (const float4*)(agg + (size_t)node * 32);
#pragma unroll
    for (int f = 0; f < 8; f++) {
        float4 v = a4[f];
        in[4 * f] = v.x; in[4 * f + 1] = v.y; in[4 * f + 2] = v.z; in[4 * f + 3] = v.w;
    }
    float p = 0.f;
#pragma unroll
    for (int cb = 0; cb < 4; cb++) {
        float o[16];
#pragma unroll
        for (int c = 0; c < 16; c++) o[c] = b2[cb * 16 + c];
#pragma unroll
        for (int k = 0; k < 32; k++) {
            float ik = in[k];
#pragma unroll
            for (int c = 0; c < 16; c++) o[c] += ik * W2[k * 64 + cb * 16 + c];
        }
#pragma unroll
        for (int c = 0; c < 16; c++) p += fmaxf(o[c], 0.f) * W3[cb * 16 + c];
    }
    t2[node] = p * dinv[node];
}

// ---------------- Layer-3 pull (2 nodes/wave) + bias + sigmoid ----------------

__global__ void __launch_bounds__(256) k_pull1_sig(const int* __restrict__ rowstart,
                                                   const int* __restrict__ csr_src,
                                                   const float* __restrict__ dinv,
                                                   const float* __restrict__ t2,
                                                   const float* __restrict__ b3,
                                                   float* __restrict__ out, int n) {
    int tid = blockIdx.x * blockDim.x + threadIdx.x;
    int wid = tid >> 5;                  // 32 lanes per node
    if (wid >= n) return;
    int lane32 = threadIdx.x & 31;
    int beg = rowstart[wid], end = rowstart[wid + 1];
    float acc = 0.f;
    for (int k = beg + lane32; k < end; k += 32)
        acc += t2[__builtin_nontemporal_load(csr_src + k)];
#pragma unroll
    for (int off = 1; off < 32; off <<= 1) acc += __shfl_xor(acc, off);
    if (lane32 == 0) {
        float v = (acc + t2[wid]) * dinv[wid] + b3[0];
        out[wid] = 1.0f / (1.0f + expf(-v));
    }
}

// ---------------- launch ----------------

extern "C" void kernel_launch(void* const* d_in, const int* in_sizes, int n_in,
                              void* d_out, int out_size, void* d_ws, size_t ws_size,
                              hipStream_t stream) {
    const float* x  = (const float*)d_in[0];
    const int*   ei = (const int*)d_in[1];
    const float* W1 = (const float*)d_in[2];
    const float* b1 = (const float*)d_in[3];
    const float* W2 = (const float*)d_in[4];
    const float* b2 = (const float*)d_in[5];
    const float* W3 = (const float*)d_in[6];
    const float* b3 = (const float*)d_in[7];

    const int n = in_sizes[0] / 16;
    const int e = in_sizes[1] / 2;
    const int* src = ei;
    const int* dst = ei + e;
    const int nbuk = cdiv(n, CW);   // 196 for n=100000

    auto rup = [](size_t v) { return (v + 15) & ~(size_t)15; };
    char* wp = (char*)d_ws;
    auto alloc = [&](size_t elems) { void* p = wp; wp += rup(elems) * 4; return p; };
    int*   bcnt     = (int*)  alloc(MAXBUKC);
    int*   boff     = (int*)  alloc(MAXBUKC + 1);
    int*   gcur     = (int*)  alloc(MAXBUKC);
    float* dinv     = (float*)alloc(n);
    int*   rowstart = (int*)  alloc(n + 1);
    int*   ebuf     = (int*)  alloc(e);
    int*   csr_src  = (int*)  alloc(e);
    unsigned int* xs  = (unsigned int*)alloc((size_t)8 * n);   // 16 bf16 / node
    unsigned int* h1s = (unsigned int*)alloc((size_t)16 * n);  // 32 bf16 / node
    float* agg16    = (float*)alloc((size_t)16 * n);
    float* agg32    = (float*)alloc((size_t)32 * n);
    float* t2       = (float*)alloc(n);

    float* out = (float*)d_out;
    const int B = 256;
    const int pullGrid = cdiv(n * 64, B);

    hipMemsetAsync(bcnt, 0, MAXBUKC * 4, stream);
    k_bhist<<<cdiv(e, 4096), B, 0, stream>>>(dst, bcnt, e, nbuk);
    k_bscan<<<1, 256, 0, stream>>>(bcnt, boff, gcur, nbuk, e);
    k_bscatter<<<cdiv(e, EPB), B, 0, stream>>>(src, dst, gcur, ebuf, e, nbuk);
    k_csr2<<<nbuk, CW, 0, stream>>>(ebuf, boff, rowstart, csr_src, dinv, n, e);
    k_xscale<<<cdiv(n * 4, B), B, 0, stream>>>(x, dinv, xs, n * 4);

    // Layer 1
    k_pull16<<<pullGrid, B, 0, stream>>>(rowstart, csr_src, dinv, xs, agg16, n);
    k_dense1<<<cdiv(n, B), B, 0, stream>>>(agg16, dinv, W1, b1, h1s, n);

    // Layer 2
    k_pull32<<<pullGrid, B, 0, stream>>>(rowstart, csr_src, dinv, h1s, agg32, n);
    k_dense2<<<cdiv(n, B), B, 0, stream>>>(agg32, dinv, W2, b2, W3, t2, n);

    // Layer 3
    k_pull1_sig<<<cdiv(n * 32, B), B, 0, stream>>>(rowstart, csr_src, dinv, t2, b3, out, n);
}